// Round 2
// 371.379 us; speedup vs baseline: 1.0429x; 1.0429x over previous
//
#include <hip/hip_runtime.h>
#include <math.h>

#define D_MODEL 256
#define N_EXP   16
#define N_VIEWS 3
#define N_TOK   8192
#define TOPK    4
#define HDIM    1024
#define CH      64
#define NCH     16
#define NSUB    32             // 32-col K sub-chunks of HDIM for the ffn pipeline
#define ROWS    64             // rows per ffn tile
#define NGROUP  48
#define GCAP    8192           // fixed capacity per (view,expert) group
#define REC_ELTS 32768         // chunk record: W1 half (16384) + W2 half (16384) shorts

typedef short s16x8 __attribute__((ext_vector_type(8)));
typedef float f32x4 __attribute__((ext_vector_type(4)));

__device__ __forceinline__ unsigned short f2bf(float x) {
    union { float f; unsigned u; } a; a.f = x;
    unsigned r = a.u + 0x7FFFu + ((a.u >> 16) & 1u);   // RNE
    return (unsigned short)(r >> 16);
}

// async global -> LDS, 16 B per lane; LDS dst is wave-uniform base + lane*16
__device__ __forceinline__ void dma16(const unsigned short* gp, unsigned short* lp) {
    __builtin_amdgcn_global_load_lds(
        (const __attribute__((address_space(1))) unsigned int*)gp,
        (__attribute__((address_space(3))) unsigned int*)lp, 16, 0, 0);
}

// stage one 16 KB W1 sub-chunk (sc = 0..31) out of the existing CH=64 records:
// record c = sc>>1, half h = sc&1. The W1 half layout idx=(ks*4+nt)*64+lane
// makes sub-chunk h the 8 contiguous 2KB runs at (ks*4+2h)*512 shorts.
// 8 waves x 2 dma16 x 1KB. LDS run ks -> ldst[ks*1024 .. +1024).
__device__ __forceinline__ void dma_sub(const unsigned short* wrec0, int sc,
                                        unsigned short* ldst, int wave, int lane) {
    const unsigned short* g = wrec0 + (size_t)(sc >> 1) * REC_ELTS
                                    + (size_t)((wave * 4 + (sc & 1) * 2) * 512);
    dma16(g + lane * 8,       ldst + wave * 1024);
    dma16(g + 512 + lane * 8, ldst + wave * 1024 + 512);
}

// ------------------------------------------------------------------
// fused prep: blocks [0,512) build Wf fragment records via coalesced
// LDS-transpose (wfrag role); blocks [512,896) do routing + group fill.
// (UNCHANGED: kept byte-identical for clean attribution of the non-ffn
//  residue; prep is the next optimization target once ffn pipeline lands.)
//
// W1 half: idx=(ks*4+nt)*64+lane : elem = W1[e][ks*32+(lane>>4)*8+j][c*64+nt*16+(lane&15)]
// W2 half: idx=(ks2*16+nt)*64+lane: elem = W2[e][c*64+ks2*32+(lane>>4)*8+j][nt*16+(lane&15)]
// ------------------------------------------------------------------
#define T1_STRIDE 65    // 256 x 65 f32 = 66560 B
#define T2_STRIDE 257   // 64 x 257 f32 = 65792 B

__global__ __launch_bounds__(256) void prep_kernel(
    const float* __restrict__ v0, const float* __restrict__ v1, const float* __restrict__ v2,
    const float* __restrict__ rw, const float* __restrict__ keys,
    const float* __restrict__ W1, const float* __restrict__ W2,
    unsigned short* __restrict__ Wf, unsigned short* __restrict__ Xbf,
    int* __restrict__ counts, int* __restrict__ rowTok, float* __restrict__ rowGate)
{
    __shared__ __align__(16) char smem[256 * T1_STRIDE * 4];   // 66560 B, role-unioned

    int bid = blockIdx.x;
    int tid = threadIdx.x;
    if (bid < 512) {
        // ---- wfrag role ----
        int c = bid & 15, e = (bid >> 4) & 15, z = bid >> 8;
        unsigned short* dst = Wf + (size_t)(e * NCH + c) * REC_ELTS;
        if (z == 0) {
            float* T1 = (float*)smem;
            const float* src = W1 + (size_t)e * 256 * 1024 + c * 64;
            #pragma unroll
            for (int p = 0; p < 16; p++) {
                int k = p * 16 + (tid >> 4), c4 = (tid & 15) * 4;
                float4 v = *(const float4*)(src + (size_t)k * 1024 + c4);
                T1[k * T1_STRIDE + c4]     = v.x;
                T1[k * T1_STRIDE + c4 + 1] = v.y;
                T1[k * T1_STRIDE + c4 + 2] = v.z;
                T1[k * T1_STRIDE + c4 + 3] = v.w;
            }
            __syncthreads();
            #pragma unroll
            for (int i = 0; i < 8; i++) {
                int idx = tid + i * 256;
                int lane = idx & 63, nt = (idx >> 6) & 3, ks = idx >> 8;
                int nl = nt * 16 + (lane & 15);
                int kbase = ks * 32 + (lane >> 4) * 8;
                s16x8 o;
                #pragma unroll
                for (int j = 0; j < 8; j++) o[j] = (short)f2bf(T1[(kbase + j) * T1_STRIDE + nl]);
                *(s16x8*)(dst + (size_t)idx * 8) = o;
            }
        } else {
            float* T2 = (float*)smem;
            const float* src = W2 + ((size_t)e * 1024 + c * 64) * 256;
            #pragma unroll
            for (int p = 0; p < 16; p++) {
                int k2l = p * 4 + (tid >> 6), c4 = (tid & 63) * 4;
                float4 v = *(const float4*)(src + (size_t)k2l * 256 + c4);
                T2[k2l * T2_STRIDE + c4]     = v.x;
                T2[k2l * T2_STRIDE + c4 + 1] = v.y;
                T2[k2l * T2_STRIDE + c4 + 2] = v.z;
                T2[k2l * T2_STRIDE + c4 + 3] = v.w;
            }
            __syncthreads();
            dst += 16384;
            #pragma unroll
            for (int i = 0; i < 8; i++) {
                int idx = tid + i * 256;
                int lane = idx & 63, ntile = (idx >> 6) & 15, ks2 = idx >> 10;
                int n = ntile * 16 + (lane & 15);
                int kbase = ks2 * 32 + (lane >> 4) * 8;
                s16x8 o;
                #pragma unroll
                for (int j = 0; j < 8; j++) o[j] = (short)f2bf(T2[(kbase + j) * T2_STRIDE + n]);
                *(s16x8*)(dst + (size_t)idx * 8) = o;
            }
        }
        return;
    }

    // ---- route + fill role: 64 tokens per block ----
    float* cwS  = (float*)smem;                      // 16 KB
    float* knS  = (float*)(smem + 16384);            // 64 B
    int*   lcnt = (int*)(smem + 16448);              // 64 B
    int*   eIdx = (int*)(smem + 16512);              // 1 KB: [tok_local*4+k]
    float* gV   = (float*)(smem + 17536);            // 1 KB
    int*  lbase = (int*)(smem + 18560);              // 64 B

    int rb = bid - 512;
    int view = rb >> 7, xb = rb & 127;
    const float* src = view == 0 ? v0 : (view == 1 ? v1 : v2);
    for (int i = tid; i < N_EXP * D_MODEL; i += 256)
        cwS[i] = rw[view * N_EXP * D_MODEL + i] + 2.0f * keys[i];
    if (tid < N_EXP) {
        const float4* kp = (const float4*)(keys + tid * D_MODEL);
        float s = 0.f;
        for (int d = 0; d < 64; d++) { float4 k = kp[d]; s += k.x*k.x + k.y*k.y + k.z*k.z + k.w*k.w; }
        knS[tid] = s; lcnt[tid] = 0;
    }
    __syncthreads();

    int wave = tid >> 6, lane = tid & 63;
    for (int t = 0; t < 16; t++) {
        int tl = wave * 16 + t;                      // token local 0..63
        int token = xb * 64 + tl;
        float4 v = ((const float4*)(src + (size_t)token * D_MODEL))[lane];
        ushort4 xo; xo.x = f2bf(v.x); xo.y = f2bf(v.y); xo.z = f2bf(v.z); xo.w = f2bf(v.w);
        ((ushort4*)(Xbf + ((size_t)view * N_TOK + token) * D_MODEL))[lane] = xo;
        float lg[N_EXP];
        #pragma unroll
        for (int e = 0; e < N_EXP; e++) {
            float4 w = *(const float4*)&cwS[e * D_MODEL + lane * 4];
            float p = v.x * w.x + v.y * w.y + v.z * w.z + v.w * w.w;
            #pragma unroll
            for (int s = 32; s > 0; s >>= 1) p += __shfl_xor(p, s, 64);
            lg[e] = p - knS[e];
        }
        int idxs[TOPK]; float vals[TOPK];
        #pragma unroll
        for (int k = 0; k < TOPK; k++) {
            float best = -1e30f; int bi = 0;
            #pragma unroll
            for (int e = 0; e < N_EXP; e++)
                if (lg[e] > best) { best = lg[e]; bi = e; }
            idxs[k] = bi; vals[k] = best;
            #pragma unroll
            for (int e = 0; e < N_EXP; e++)
                lg[e] = (e == bi) ? -1e30f : lg[e];
        }
        float m = vals[0], s = 0.f, ex[TOPK];
        #pragma unroll
        for (int k = 0; k < TOPK; k++) { ex[k] = __expf(vals[k] - m); s += ex[k]; }
        float inv = 1.0f / s;
        if (lane == 0) {
            #pragma unroll
            for (int k = 0; k < TOPK; k++) {
                eIdx[tl * 4 + k] = idxs[k];
                gV[tl * 4 + k] = ex[k] * inv;
                atomicAdd(&lcnt[idxs[k]], 1);
            }
        }
    }
    __syncthreads();
    if (tid < N_EXP)
        lbase[tid] = lcnt[tid] ? atomicAdd(&counts[view * N_EXP + tid], lcnt[tid]) : 0;
    __syncthreads();
    if (tid < N_EXP) {
        int e = tid;
        int dstbase = (view * N_EXP + e) * GCAP + lbase[e];
        int c = 0;
        for (int i = 0; i < 256; i++) {
            if (eIdx[i] == e) {
                rowTok[dstbase + c]  = xb * 64 + (i >> 2);
                rowGate[dstbase + c] = gV[i];
                c++;
            }
        }
    }
}

// ------------------------------------------------------------------
// fused FFN v12: depth-3 counted-vmcnt pipeline, ORDER-ROBUST version.
//  - K split into 32 sub-chunks of 32 HDIM cols inside existing Wf records.
//  - W1 QUAD-buffered (4x16 KB), Hc dbuf (2x4 KB) -> 72 KB LDS, 2 blocks/CU.
//  - Every dma_sub is pinned in its own sched_barrier(0) region, so DMAs are
//    provably the NEWEST VMEM ops at each boundary. Counted waits:
//      prologue vmcnt(4)  -> retires DMA(0) + all earlier loads
//      boundary vmcnt(9)  -> at boundary 0 retires DMA(1); later boundaries
//                            are additionally covered by the FIFO chain:
//    GEMM2(cc)'s compiler wait on w2r(cc) (issued BEFORE DMA(cc+3), AFTER
//    DMA(cc+2)) retires DMA(cc+2) per-wave; the phase barrier extends this
//    to all waves before GEMM1(cc+2) reads the buffer. No count assumptions
//    about non-DMA VMEM ordering remain.
//  - No tail dummy DMAs (skip when cc+3 >= NSUB); explicit vmcnt(0) after
//    the loop so NO LDS-DMA is outstanding at s_endpgm (v11 crash suspect).
//  - T5 setprio around MFMA clusters; GEMM1 as 2 accumulation chains.
// STATIC schedule: xcd = blockIdx&7 owns experts {2x,2x+1} x 3 views.
// ------------------------------------------------------------------
__global__ __launch_bounds__(512, 4) void ffn_kernel(
    const unsigned short* __restrict__ Xbf, const unsigned short* __restrict__ Wf,
    const float* __restrict__ b1, const float* __restrict__ b2,
    const int* __restrict__ counts, const int* __restrict__ rowTok,
    const float* __restrict__ rowGate, float* __restrict__ out)
{
    __shared__ __align__(16) unsigned short W1buf[4][8192];   // 64 KB quad buffer
    __shared__ __align__(16) unsigned short Hc[2][2048];      // 8 KB dbuf, A-frag order

    int s = blockIdx.x;
    int xcd = s & 7, k = s >> 3;
    int j = k % 6, ti = k / 6;                 // j: group-of-xcd, ti: tile 0..127
    int e = 2 * xcd + (j & 1), view = j >> 1;
    int g = view * N_EXP + e;
    int L = counts[g];
    int r0 = ti * ROWS;
    if (r0 >= L) return;                       // block-uniform: safe before barriers
    int base = g * GCAP;

    int tid = threadIdx.x;
    int wave = tid >> 6, lane = tid & 63, lmod = lane & 15, quad = lane >> 4;

    const unsigned short* wchunk = Wf + (size_t)e * NCH * REC_ELTS;

    int mt1 = wave & 3, nh = wave >> 2;          // GEMM1 roles: 16 rows x 16 cols
    int ms  = wave & 1, ns = wave >> 1;          // GEMM2 roles: 32 rows x 64 cols

    // X A-fragments for m-tile mt1 (32 VGPR); tok direct from global.
    s16x8 areg[8];
    {
        int gr = r0 + mt1 * 16 + lmod;
        int token = (gr < L) ? rowTok[base + gr] : 0;
        const unsigned short* xp = Xbf + ((size_t)view * N_TOK + token) * D_MODEL;
        #pragma unroll
        for (int ks = 0; ks < 8; ks++)
            areg[ks] = *(const s16x8*)(xp + ks * 32 + quad * 8);
    }
    float bbCur = b1[e * HDIM + nh * 16 + lmod];   // sub-0 bias (older than all DMAs)

    f32x4 acc2[2][4];
    #pragma unroll
    for (int i = 0; i < 2; i++)
        #pragma unroll
        for (int jj = 0; jj < 4; jj++) acc2[i][jj] = (f32x4){0.f, 0.f, 0.f, 0.f};

    // ---- prologue: each DMA pinned in its own region -> issue order certain.
    __builtin_amdgcn_sched_barrier(0);
    dma_sub(wchunk, 0, &W1buf[0][0], wave, lane);
    __builtin_amdgcn_sched_barrier(0);
    dma_sub(wchunk, 1, &W1buf[1][0], wave, lane);
    __builtin_amdgcn_sched_barrier(0);
    dma_sub(wchunk, 2, &W1buf[2][0], wave, lane);
    __builtin_amdgcn_sched_barrier(0);
    // retire DMA(0) + every earlier load; keep DMA(1),DMA(2) (newest 4) in flight
    asm volatile("s_waitcnt vmcnt(4)" ::: "memory");
    __builtin_amdgcn_sched_barrier(0);
    __builtin_amdgcn_s_barrier();                  // buf0 valid for all waves
    __builtin_amdgcn_sched_barrier(0);

    s16x8 w2r[4] = {};

    #pragma unroll 1
    for (int cc = 0; cc < NSUB; cc++) {
        // ---- compute region (internal VMEM order irrelevant) ----
        int bn = (cc + 1 < NSUB) ? cc + 1 : NSUB - 1;
        float bbNext = b1[e * HDIM + bn * 32 + nh * 16 + lmod];

        // GEMM1(cc): 16 rows x 16 cols per wave, K=256, 2 acc chains
        const unsigned short* w1s = &W1buf[cc & 3][0];
        f32x4 a1a = (f32x4){0.f, 0.f, 0.f, 0.f};
        f32x4 a1b = (f32x4){0.f, 0.f, 0.f, 0.f};
        __builtin_amdgcn_s_setprio(1);
        #pragma unroll
        for (int ks = 0; ks < 8; ks += 2) {
            s16x8 bw0 = *(const s16x8*)(w1s + ks * 1024 + nh * 512 + lane * 8);
            s16x8 bw1 = *(const s16x8*)(w1s + (ks + 1) * 1024 + nh * 512 + lane * 8);
            a1a = __builtin_amdgcn_mfma_f32_16x16x32_bf16(areg[ks],     bw0, a1a, 0, 0, 0);
            a1b = __builtin_amdgcn_mfma_f32_16x16x32_bf16(areg[ks + 1], bw1, a1b, 0, 0, 0);
        }
        __builtin_amdgcn_s_setprio(0);

        // bias + gelu -> Hc[cc&1] (A-frag order for GEMM2)
        {
            unsigned short* hd = &Hc[cc & 1][0];
            int bo = mt1 * 512 + (nh * 2 + (lmod >> 3)) * 128 + quad * 32 + (lmod & 7);
            #pragma unroll
            for (int r = 0; r < 4; r++) {
                float h = a1a[r] + a1b[r] + bbCur;
                float u = h * (0.7978845608f + 0.0356774081f * h * h);
                float ex2 = __expf(2.f * u);
                float tn = 1.f - 2.f * __builtin_amdgcn_rcpf(1.f + ex2);
                hd[bo + r * 8] = f2bf(0.5f * h * (1.f + tn));
            }
        }

        // GEMM2(cc-1): 32 rows x 64 cols per wave, K=32 (consumes w2r(cc-1);
        // the compiler's wait here retires DMA(cc+1) per-wave -> with the
        // barrier below this is the W1-freshness chain)
        if (cc > 0) {
            const unsigned short* hs = &Hc[(cc - 1) & 1][0];
            s16x8 afr[2];
            #pragma unroll
            for (int mt = 0; mt < 2; mt++)
                afr[mt] = *(const s16x8*)(hs + ((ms * 2 + mt) * 64 + lane) * 8);
            __builtin_amdgcn_s_setprio(1);
            #pragma unroll
            for (int nt = 0; nt < 4; nt++)
                #pragma unroll
                for (int mt = 0; mt < 2; mt++)
                    acc2[mt][nt] = __builtin_amdgcn_mfma_f32_16x16x32_bf16(
                        afr[mt], w2r[nt], acc2[mt][nt], 0, 0, 0);
            __builtin_amdgcn_s_setprio(0);
        }

        // reload w2r with sub cc's W2 B-frags (direct from global/L2; aged
        // across the barrier, consumed next phase)
        {
            const unsigned short* w2p = wchunk + (size_t)(cc >> 1) * REC_ELTS + 16384
                                        + (size_t)(((cc & 1) * 16 + ns * 4) * 512);
            #pragma unroll
            for (int nt = 0; nt < 4; nt++)
                w2r[nt] = *(const s16x8*)(w2p + nt * 512 + lane * 8);
        }

        // ---- DMA region: pinned, provably the newest VMEM ops ----
        __builtin_amdgcn_sched_barrier(0);
        if (cc + 3 < NSUB)
            dma_sub(wchunk, cc + 3, &W1buf[(cc + 3) & 3][0], wave, lane);
        __builtin_amdgcn_sched_barrier(0);

        bbCur = bbNext;

        // ---- phase boundary: counted wait (no drain) + barrier ----
        asm volatile("s_waitcnt vmcnt(9) lgkmcnt(0)" ::: "memory");
        __builtin_amdgcn_sched_barrier(0);
        __builtin_amdgcn_s_barrier();
        __builtin_amdgcn_sched_barrier(0);
    }

    // drain everything (incl. any LDS-DMA) BEFORE kernel end — never exit
    // with outstanding global_load_lds
    asm volatile("s_waitcnt vmcnt(0)" ::: "memory");

    // ---- peeled GEMM2 for sub 31 (Hc published by the final barrier)
    {
        const unsigned short* hs = &Hc[(NSUB - 1) & 1][0];
        s16x8 afr[2];
        #pragma unroll
        for (int mt = 0; mt < 2; mt++)
            afr[mt] = *(const s16x8*)(hs + ((ms * 2 + mt) * 64 + lane) * 8);
        #pragma unroll
        for (int nt = 0; nt < 4; nt++)
            #pragma unroll
            for (int mt = 0; mt < 2; mt++)
                acc2[mt][nt] = __builtin_amdgcn_mfma_f32_16x16x32_bf16(
                    afr[mt], w2r[nt], acc2[mt][nt], 0, 0, 0);
    }

    // epilogue: out[token] += gate * (acc2 + b2); tok/gate direct from global
    int   tokR[2][4];
    float gateR[2][4];
    #pragma unroll
    for (int mt = 0; mt < 2; mt++)
        #pragma unroll
        for (int r = 0; r < 4; r++) {
            int gr = r0 + (ms * 2 + mt) * 16 + quad * 4 + r;
            bool ok = gr < L;
            tokR[mt][r]  = ok ? rowTok[base + gr] : -1;
            gateR[mt][r] = ok ? rowGate[base + gr] : 0.f;
        }
    #pragma unroll
    for (int nt = 0; nt < 4; nt++) {
        int col = (ns * 4 + nt) * 16 + lmod;
        float b2v = b2[e * D_MODEL + col];
        #pragma unroll
        for (int mt = 0; mt < 2; mt++) {
            #pragma unroll
            for (int r = 0; r < 4; r++) {
                if (tokR[mt][r] >= 0) {
                    atomicAdd(&out[(size_t)tokR[mt][r] * D_MODEL + col],
                              gateR[mt][r] * (acc2[mt][nt][r] + b2v));
                }
            }
        }
    }
}

// ------------------------------------------------------------------
extern "C" void kernel_launch(void* const* d_in, const int* in_sizes, int n_in,
                              void* d_out, int out_size, void* d_ws, size_t ws_size,
                              hipStream_t stream)
{
    const float* v0   = (const float*)d_in[0];
    const float* v1   = (const float*)d_in[1];
    const float* v2   = (const float*)d_in[2];
    const float* rw   = (const float*)d_in[3];
    const float* keys = (const float*)d_in[4];
    const float* W1   = (const float*)d_in[5];
    const float* b1   = (const float*)d_in[6];
    const float* W2   = (const float*)d_in[7];
    const float* b2   = (const float*)d_in[8];
    float* out = (float*)d_out;

    char* p = (char*)d_ws;
    unsigned short* Xbf = (unsigned short*)p; p += (size_t)N_VIEWS * N_TOK * D_MODEL * 2;
    unsigned short* Wf  = (unsigned short*)p; p += (size_t)N_EXP * NCH * REC_ELTS * 2;
    int*   counts = (int*)p;   p += 256;
    int*   rowTok = (int*)p;   p += (size_t)NGROUP * GCAP * 4;
    float* rowGate= (float*)p; p += (size_t)NGROUP * GCAP * 4;

    hipMemsetAsync(counts, 0, NGROUP * sizeof(int), stream);
    hipMemsetAsync(out, 0, (size_t)out_size * sizeof(float), stream);

    prep_kernel<<<896, 256, 0, stream>>>(v0, v1, v2, rw, keys, W1, W2,
                                         Wf, Xbf, counts, rowTok, rowGate);
    ffn_kernel<<<8 * 768, 512, 0, stream>>>(Xbf, Wf, b1, b2, counts,
                                            rowTok, rowGate, out);
}